// Round 7
// baseline (341.087 us; speedup 1.0000x reference)
//
#include <hip/hip_runtime.h>

#define N_NODES 50000
#define IN_SIZE 512
#define HID 128
#define OUT 64
#define NB 256                 // coarse scatter blocks
#define SHIFT 7                // bucket = dst >> 7  (128 nodes per bucket)
#define NBUCK 391              // ceil(50000/128)
#define SB 64                  // src-histogram blocks (100KB LDS each)
#define NBINS32 25000          // 50000 uint16 bins packed in uint32

typedef _Float16 f16x8 __attribute__((ext_vector_type(8)));
typedef _Float16 f16x2 __attribute__((ext_vector_type(2)));
typedef float    f32x4 __attribute__((ext_vector_type(4)));

// ---------- inline int64-vs-int32 layout detection (per block, no extra dispatch) ----------
__device__ __forceinline__ bool detect_w(const int* p, int t, int* sh) {
    if (t < 64) {
        unsigned long long m = __ballot(p[2 * t + 1] == 0);
        if (t == 0) *sh = (m == ~0ull) ? 1 : 0;
    }
    __syncthreads();
    return *sh != 0;
}

__device__ __forceinline__ int load_idx(const void* p, int e, bool w) {
    return w ? (int)((const long long*)p)[e] : ((const int*)p)[e];
}

// ---------- pass 1: per-block coarse histogram of dst (LDS only) + appended weight-transpose blocks ----------
__global__ __launch_bounds__(256) void k_chist_wt(const void* __restrict__ dstp,
                                                  int* __restrict__ hist, int E, int EPB,
                                                  const float* __restrict__ W1, _Float16* __restrict__ W1T,
                                                  const float* __restrict__ W2, _Float16* __restrict__ W2T) {
    const int t = threadIdx.x, b = blockIdx.x;
    if (b >= NB) {   // weight transpose tail blocks
        int i = (b - NB) * 256 + t;
        if (i < IN_SIZE * HID) {
            int k = i >> 7, n = i & (HID - 1);
            W1T[(size_t)n * IN_SIZE + k] = (_Float16)W1[i];
        } else {
            int j = i - IN_SIZE * HID;
            if (j < HID * OUT) {
                int k = j >> 6, n = j & (OUT - 1);
                W2T[(size_t)n * HID + k] = (_Float16)W2[j];
            }
        }
        return;
    }
    __shared__ int bins[NBUCK];
    __shared__ int shw;
    for (int i = t; i < NBUCK; i += 256) bins[i] = 0;
    bool w = detect_w((const int*)dstp, t, &shw);
    __syncthreads();
    int eend = min(E, (b + 1) * EPB);
    for (int e = b * EPB + t; e < eend; e += 256)
        atomicAdd(&bins[load_idx(dstp, e, w) >> SHIFT], 1);
    __syncthreads();
    for (int i = t; i < NBUCK; i += 256) hist[i * NB + b] = bins[i];
}

// ---------- src out-degree: privatized packed-uint16 LDS histograms ----------
__global__ __launch_bounds__(256) void k_srchist(const void* __restrict__ srcp,
                                                 unsigned int* __restrict__ partial, int E, int ESB) {
    __shared__ unsigned int bins[NBINS32];   // 100 KB
    __shared__ int shw;
    const int t = threadIdx.x, b = blockIdx.x;
    for (int i = t; i < NBINS32; i += 256) bins[i] = 0;
    bool w = detect_w((const int*)srcp, t, &shw);
    __syncthreads();
    int eend = min(E, (b + 1) * ESB);
    for (int e = b * ESB + t; e < eend; e += 256) {
        int s = load_idx(srcp, e, w);
        atomicAdd(&bins[s >> 1], 1u << ((s & 1) << 4));
    }
    __syncthreads();
    for (int i = t; i < NBINS32; i += 256) partial[(size_t)b * NBINS32 + i] = bins[i];
}

// ---------- pass 2: scan hist (bucket-major) ----------
__global__ __launch_bounds__(256) void k_scanA(int* __restrict__ hist, int* __restrict__ bsum) {
    __shared__ int s[256];
    const int t = threadIdx.x, g = blockIdx.x;
    int v = hist[g * NB + t];
    s[t] = v;
    __syncthreads();
    for (int off = 1; off < 256; off <<= 1) {
        int u = (t >= off) ? s[t - off] : 0;
        __syncthreads();
        s[t] += u;
        __syncthreads();
    }
    hist[g * NB + t] = s[t] - v;
    if (t == 255) bsum[g] = s[255];
}

__global__ __launch_bounds__(512) void k_scanB(const int* __restrict__ bsum, int* __restrict__ bb) {
    __shared__ int s[512];
    const int t = threadIdx.x;
    int v = (t < NBUCK) ? bsum[t] : 0;
    s[t] = v;
    __syncthreads();
    for (int off = 1; off < 512; off <<= 1) {
        int u = (t >= off) ? s[t - off] : 0;
        __syncthreads();
        s[t] += u;
        __syncthreads();
    }
    if (t <= NBUCK) bb[t] = s[t] - v;     // bb[NBUCK] = total = E
}

// ---------- pass 3: coarse scatter, packed (src | dl<<16) ----------
__global__ __launch_bounds__(256) void k_cscatter(const void* __restrict__ srcp,
                                                  const void* __restrict__ dstp,
                                                  const int* __restrict__ hist,
                                                  const int* __restrict__ bb,
                                                  unsigned int* __restrict__ tmp,
                                                  int E, int EPB) {
    __shared__ int cur[NBUCK];
    __shared__ int shw;
    const int t = threadIdx.x, b = blockIdx.x;
    for (int i = t; i < NBUCK; i += 256) cur[i] = hist[i * NB + b] + bb[i];
    bool w = detect_w((const int*)dstp, t, &shw);
    __syncthreads();
    int eend = min(E, (b + 1) * EPB);
    for (int e = b * EPB + t; e < eend; e += 256) {
        int s = load_idx(srcp, e, w);
        int d = load_idx(dstp, e, w);
        int pos = atomicAdd(&cur[d >> SHIFT], 1);
        tmp[pos] = (unsigned int)s | ((unsigned int)(d & 127) << 16);
    }
}

// ---------- pass 4: fine count + scan + scatter; writes rp, innorm, onorm (sred fused) ----------
__global__ __launch_bounds__(256) void k_fine(const unsigned int* __restrict__ tmp,
                                              const int* __restrict__ bb,
                                              const unsigned int* __restrict__ partial,
                                              int* __restrict__ rp,
                                              int* __restrict__ esrc,
                                              float* __restrict__ innorm,
                                              float* __restrict__ onorm) {
    __shared__ int fcnt[128];
    __shared__ int sc[128];
    __shared__ int fcur[128];
    const int t = threadIdx.x, u = blockIdx.x;
    const int e0 = bb[u], e1 = bb[u + 1];
    if (t < 128) fcnt[t] = 0;
    __syncthreads();
    for (int e = e0 + t; e < e1; e += 256)
        atomicAdd(&fcnt[tmp[e] >> 16], 1);
    // fused sred: this block owns packed words u*64 .. u*64+63 (= its own 128 nodes)
    if (t < 64) {
        int wd = u * 64 + t;
        if (wd < NBINS32) {
            int c0 = 0, c1 = 0;
            for (int b = 0; b < SB; ++b) {
                unsigned int v = partial[(size_t)b * NBINS32 + wd];
                c0 += (int)(v & 0xFFFFu);
                c1 += (int)(v >> 16);
            }
            if (c0 < 1) c0 = 1;
            if (c1 < 1) c1 = 1;
            onorm[2 * wd]     = 1.0f / sqrtf((float)c0);
            if (2 * wd + 1 < N_NODES) onorm[2 * wd + 1] = 1.0f / sqrtf((float)c1);
        }
    }
    __syncthreads();
    if (t < 128) sc[t] = fcnt[t];
    __syncthreads();
    for (int off = 1; off < 128; off <<= 1) {
        int v = (t < 128 && t >= off) ? sc[t - off] : 0;
        __syncthreads();
        if (t < 128) sc[t] += v;
        __syncthreads();
    }
    if (t < 128) {
        int base = e0 + sc[t] - fcnt[t];
        fcur[t] = base;
        int node = u * 128 + t;
        if (node < N_NODES) {
            rp[node] = base;
            int c = fcnt[t]; if (c < 1) c = 1;
            innorm[node] = 1.0f / sqrtf((float)c);
        }
    }
    if (u == NBUCK - 1 && t == 0) rp[N_NODES] = e1;
    __syncthreads();
    for (int e = e0 + t; e < e1; e += 256) {
        unsigned int p = tmp[e];
        int pos = atomicAdd(&fcur[p >> 16], 1);
        esrc[pos] = (int)(p & 0xFFFFu);
    }
}

// ---------- GEMM1 (MFMA fp16): X1[n,:] = fp16( out_norm[n] * (feat[n,:] @ W1) ) ----------
#define LDA 40  // 32 + 8 halfs pad (16B)
__global__ __launch_bounds__(256) void k_gemm1_mfma(const float* __restrict__ A,
                                                    const _Float16* __restrict__ BT,
                                                    const float* __restrict__ onorm,
                                                    _Float16* __restrict__ X) {
    __shared__ _Float16 As[64 * LDA];
    __shared__ _Float16 Bs[128 * LDA];
    const int tid  = threadIdx.x;
    const int wave = tid >> 6, lane = tid & 63;
    const int lm = lane & 15, lq = lane >> 4;
    const int row0 = blockIdx.x * 64;

    const int ar = tid >> 2, aq = tid & 3;
    int arow = row0 + ar; if (arow >= N_NODES) arow = N_NODES - 1;
    const float* aptr = A + (size_t)arow * IN_SIZE + aq * 8;
    _Float16* asd = &As[ar * LDA + aq * 8];
    const int bn = tid >> 1, bh = tid & 1;
    const _Float16* bptr = BT + (size_t)bn * IN_SIZE + bh * 16;
    _Float16* bsd = &Bs[bn * LDA + bh * 16];

    f32x4 acc[8];
#pragma unroll
    for (int nt = 0; nt < 8; ++nt) acc[nt] = (f32x4){0.f, 0.f, 0.f, 0.f};

    for (int k0 = 0; k0 < IN_SIZE; k0 += 32) {
        float4 a0 = *(const float4*)(aptr + k0);
        float4 a1 = *(const float4*)(aptr + k0 + 4);
        f16x8  b0 = *(const f16x8*)(bptr + k0);
        f16x8  b1 = *(const f16x8*)(bptr + k0 + 8);
        f16x8 ap = {(_Float16)a0.x, (_Float16)a0.y, (_Float16)a0.z, (_Float16)a0.w,
                    (_Float16)a1.x, (_Float16)a1.y, (_Float16)a1.z, (_Float16)a1.w};
        __syncthreads();
        *(f16x8*)asd       = ap;
        *(f16x8*)bsd       = b0;
        *(f16x8*)(bsd + 8) = b1;
        __syncthreads();
        f16x8 af = *(const f16x8*)&As[(wave * 16 + lm) * LDA + lq * 8];
#pragma unroll
        for (int nt = 0; nt < 8; ++nt) {
            f16x8 bf = *(const f16x8*)&Bs[(nt * 16 + lm) * LDA + lq * 8];
            acc[nt] = __builtin_amdgcn_mfma_f32_16x16x32_f16(af, bf, acc[nt], 0, 0, 0);
        }
    }
#pragma unroll
    for (int i = 0; i < 4; ++i) {
        int row = row0 + wave * 16 + lq * 4 + i;
        if (row < N_NODES) {
            float on = onorm[row];
            _Float16* o = X + (size_t)row * HID + lm;
#pragma unroll
            for (int nt = 0; nt < 8; ++nt)
                o[nt * 16] = (_Float16)(acc[nt][i] * on);
        }
    }
}

// ---------- fused agg1 + gemm2: block = 64 nodes ----------
// phase 1: gather-sum X1 rows -> H = fp16(relu(...)) into LDS (per-wave, 16 nodes each)
// phase 2: MFMA H[64x128] @ W2T -> X2[64x64]
#define LDK 136  // 128 + 8 halfs pad
__global__ __launch_bounds__(256) void k_agg1_gemm2(const _Float16* __restrict__ X,
                                                    const int* __restrict__ rp,
                                                    const int* __restrict__ esrc,
                                                    const float* __restrict__ innorm,
                                                    const float* __restrict__ onorm,
                                                    const float* __restrict__ b1,
                                                    const _Float16* __restrict__ W2T,
                                                    _Float16* __restrict__ X2) {
    __shared__ _Float16 Hs[64 * LDK];
    __shared__ _Float16 Ws[64 * LDK];
    const int tid  = threadIdx.x;
    const int wave = tid >> 6, lane = tid & 63;
    const int row0 = blockIdx.x * 64;

    // stage W2T (64 rows x 128 k): thread t -> row r=t>>2, chunk (t&3)*32 halfs
    {
        const int r = tid >> 2, cch = (tid & 3) * 32;
        const _Float16* wp = W2T + (size_t)r * HID + cch;
        _Float16* wd = &Ws[r * LDK + cch];
#pragma unroll
        for (int i = 0; i < 4; ++i)
            *(f16x8*)(wd + i * 8) = *(const f16x8*)(wp + i * 8);
    }

    // phase 1: each wave aggregates 16 nodes
    const int c = lane << 1;
    float2 b = *(const float2*)&b1[c];
#pragma unroll 1
    for (int i = 0; i < 16; ++i) {
        const int r = wave * 16 + i;
        const int n = row0 + r;
        if (n >= N_NODES) {
            *(f16x2*)&Hs[r * LDK + c] = (f16x2){(_Float16)0.f, (_Float16)0.f};
            continue;
        }
        const int e0 = rp[n], e1 = rp[n + 1];
        float a0 = 0.f, a1 = 0.f;
        int e = e0;
        for (; e + 3 < e1; e += 4) {
            int s0 = esrc[e], s1 = esrc[e + 1], s2 = esrc[e + 2], s3 = esrc[e + 3];
            f16x2 v0 = *(const f16x2*)&X[(size_t)s0 * HID + c];
            f16x2 v1 = *(const f16x2*)&X[(size_t)s1 * HID + c];
            f16x2 v2 = *(const f16x2*)&X[(size_t)s2 * HID + c];
            f16x2 v3 = *(const f16x2*)&X[(size_t)s3 * HID + c];
            a0 += ((float)v0.x + (float)v1.x) + ((float)v2.x + (float)v3.x);
            a1 += ((float)v0.y + (float)v1.y) + ((float)v2.y + (float)v3.y);
        }
        for (; e < e1; ++e) {
            f16x2 v = *(const f16x2*)&X[(size_t)esrc[e] * HID + c];
            a0 += (float)v.x; a1 += (float)v.y;
        }
        float inn = innorm[n], on = onorm[n];
        float h0 = fmaxf(a0 * inn + b.x, 0.f) * on;
        float h1 = fmaxf(a1 * inn + b.y, 0.f) * on;
        *(f16x2*)&Hs[r * LDK + c] = (f16x2){(_Float16)h0, (_Float16)h1};
    }
    __syncthreads();

    // phase 2: MFMA (identical to standalone gemm2)
    const int lm = lane & 15, lq = lane >> 4;
    f32x4 acc[4];
#pragma unroll
    for (int nt = 0; nt < 4; ++nt) acc[nt] = (f32x4){0.f, 0.f, 0.f, 0.f};
#pragma unroll
    for (int k0 = 0; k0 < HID; k0 += 32) {
        f16x8 af = *(const f16x8*)&Hs[(wave * 16 + lm) * LDK + k0 + lq * 8];
#pragma unroll
        for (int nt = 0; nt < 4; ++nt) {
            f16x8 bf = *(const f16x8*)&Ws[(nt * 16 + lm) * LDK + k0 + lq * 8];
            acc[nt] = __builtin_amdgcn_mfma_f32_16x16x32_f16(af, bf, acc[nt], 0, 0, 0);
        }
    }
#pragma unroll
    for (int i = 0; i < 4; ++i) {
        int row = row0 + wave * 16 + lq * 4 + i;
        if (row < N_NODES) {
            _Float16* o = X2 + (size_t)row * OUT + lm;
#pragma unroll
            for (int nt = 0; nt < 4; ++nt)
                o[nt * 16] = (_Float16)acc[nt][i];
        }
    }
}

// ---------- agg2: out = gather-sum(X2)*in_norm + b2  (fp32 out) ----------
__global__ __launch_bounds__(256) void k_agg2(const _Float16* __restrict__ X2, const int* __restrict__ rp,
                                              const int* __restrict__ esrc, const float* __restrict__ innorm,
                                              const float* __restrict__ b2, float* __restrict__ out) {
    const int n = blockIdx.x * 8 + (threadIdx.x >> 5);
    const int c = (threadIdx.x & 31) << 1;
    if (n >= N_NODES) return;
    const int e0 = rp[n], e1 = rp[n + 1];
    float a0 = 0.f, a1 = 0.f;
    int e = e0;
    for (; e + 3 < e1; e += 4) {
        int s0 = esrc[e], s1 = esrc[e + 1], s2 = esrc[e + 2], s3 = esrc[e + 3];
        f16x2 v0 = *(const f16x2*)&X2[(size_t)s0 * OUT + c];
        f16x2 v1 = *(const f16x2*)&X2[(size_t)s1 * OUT + c];
        f16x2 v2 = *(const f16x2*)&X2[(size_t)s2 * OUT + c];
        f16x2 v3 = *(const f16x2*)&X2[(size_t)s3 * OUT + c];
        a0 += ((float)v0.x + (float)v1.x) + ((float)v2.x + (float)v3.x);
        a1 += ((float)v0.y + (float)v1.y) + ((float)v2.y + (float)v3.y);
    }
    for (; e < e1; ++e) {
        f16x2 v = *(const f16x2*)&X2[(size_t)esrc[e] * OUT + c];
        a0 += (float)v.x; a1 += (float)v.y;
    }
    float inn = innorm[n];
    float2 b = *(const float2*)&b2[c];
    *(float2*)&out[(size_t)n * OUT + c] = make_float2(a0 * inn + b.x, a1 * inn + b.y);
}

extern "C" void kernel_launch(void* const* d_in, const int* in_sizes, int n_in,
                              void* d_out, int out_size, void* d_ws, size_t ws_size,
                              hipStream_t stream) {
    const float* feat = (const float*)d_in[0];
    const float* W1   = (const float*)d_in[1];
    const float* b1   = (const float*)d_in[2];
    const float* W2   = (const float*)d_in[3];
    const float* b2   = (const float*)d_in[4];
    const void*  srcp = (const void*)d_in[5];
    const void*  dstp = (const void*)d_in[6];
    const int    E    = in_sizes[5];
    float* out = (float*)d_out;

    char* w = (char*)d_ws;
    size_t off = 0;
    auto alloc = [&](size_t bytes) -> void* {
        off = (off + 255) & ~(size_t)255;
        void* p = w + off;
        off += bytes;
        return p;
    };
    int*   hist    = (int*)alloc((size_t)NBUCK * NB * 4);
    int*   bsum    = (int*)alloc((size_t)NBUCK * 4);
    int*   bb      = (int*)alloc((size_t)(NBUCK + 1) * 4);
    int*   rp      = (int*)alloc((size_t)(N_NODES + 1) * 4);
    unsigned int* spart = (unsigned int*)alloc((size_t)SB * NBINS32 * 4);
    unsigned int* tmp   = (unsigned int*)alloc((size_t)E * 4);
    int*   esrc    = (int*)alloc((size_t)E * 4);
    float* onorm   = (float*)alloc((size_t)N_NODES * 4);
    float* innorm  = (float*)alloc((size_t)N_NODES * 4);
    _Float16* W1T  = (_Float16*)alloc((size_t)IN_SIZE * HID * 2);
    _Float16* W2T  = (_Float16*)alloc((size_t)HID * OUT * 2);
    _Float16* X1   = (_Float16*)alloc((size_t)N_NODES * HID * 2);
    _Float16* X2   = (_Float16*)alloc((size_t)N_NODES * OUT * 2);
    (void)ws_size; (void)n_in; (void)out_size;

    const int EPB = (E + NB - 1) / NB;
    const int ESB = (E + SB - 1) / SB;
    const int WTB = (IN_SIZE * HID + HID * OUT + 255) / 256;

    // CSR build — no global atomics anywhere
    k_chist_wt<<<NB + WTB, 256, 0, stream>>>(dstp, hist, E, EPB, W1, W1T, W2, W2T);
    k_srchist<<<SB, 256, 0, stream>>>(srcp, spart, E, ESB);
    k_scanA<<<NBUCK, 256, 0, stream>>>(hist, bsum);
    k_scanB<<<1, 512, 0, stream>>>(bsum, bb);
    k_cscatter<<<NB, 256, 0, stream>>>(srcp, dstp, hist, bb, tmp, E, EPB);
    k_fine<<<NBUCK, 256, 0, stream>>>(tmp, bb, spart, rp, esrc, innorm, onorm);

    // dense + aggregation pipeline
    k_gemm1_mfma<<<(N_NODES + 63) / 64, 256, 0, stream>>>(feat, W1T, onorm, X1);
    k_agg1_gemm2<<<(N_NODES + 63) / 64, 256, 0, stream>>>(X1, rp, esrc, innorm, onorm, b1, W2T, X2);
    k_agg2<<<(N_NODES + 7) / 8, 256, 0, stream>>>(X2, rp, esrc, innorm, b2, out);
}

// Round 8
// 310.554 us; speedup vs baseline: 1.0983x; 1.0983x over previous
//
#include <hip/hip_runtime.h>

#define N_NODES 50000
#define IN_SIZE 512
#define HID 128
#define OUT 64
#define NB 256                 // coarse scatter blocks
#define SHIFT 7                // bucket = dst >> 7  (128 nodes per bucket)
#define NBUCK 391              // ceil(50000/128)
#define SB 64                  // src-histogram blocks (100KB LDS each)
#define NBINS32 25000          // 50000 uint16 bins packed in uint32

typedef _Float16 f16x8 __attribute__((ext_vector_type(8)));
typedef _Float16 f16x2 __attribute__((ext_vector_type(2)));
typedef float    f32x4 __attribute__((ext_vector_type(4)));

// ---------- inline int64-vs-int32 layout detection (per block, no extra dispatch) ----------
__device__ __forceinline__ bool detect_w(const int* p, int t, int* sh) {
    if (t < 64) {
        unsigned long long m = __ballot(p[2 * t + 1] == 0);
        if (t == 0) *sh = (m == ~0ull) ? 1 : 0;
    }
    __syncthreads();
    return *sh != 0;
}

__device__ __forceinline__ int load_idx(const void* p, int e, bool w) {
    return w ? (int)((const long long*)p)[e] : ((const int*)p)[e];
}

// ---------- pass 1: per-block coarse histogram of dst (LDS only) + appended weight-transpose blocks ----------
__global__ __launch_bounds__(256) void k_chist_wt(const void* __restrict__ dstp,
                                                  int* __restrict__ hist, int E, int EPB,
                                                  const float* __restrict__ W1, _Float16* __restrict__ W1T,
                                                  const float* __restrict__ W2, _Float16* __restrict__ W2T) {
    const int t = threadIdx.x, b = blockIdx.x;
    if (b >= NB) {   // weight transpose tail blocks
        int i = (b - NB) * 256 + t;
        if (i < IN_SIZE * HID) {
            int k = i >> 7, n = i & (HID - 1);
            W1T[(size_t)n * IN_SIZE + k] = (_Float16)W1[i];
        } else {
            int j = i - IN_SIZE * HID;
            if (j < HID * OUT) {
                int k = j >> 6, n = j & (OUT - 1);
                W2T[(size_t)n * HID + k] = (_Float16)W2[j];
            }
        }
        return;
    }
    __shared__ int bins[NBUCK];
    __shared__ int shw;
    for (int i = t; i < NBUCK; i += 256) bins[i] = 0;
    bool w = detect_w((const int*)dstp, t, &shw);
    __syncthreads();
    int eend = min(E, (b + 1) * EPB);
    for (int e = b * EPB + t; e < eend; e += 256)
        atomicAdd(&bins[load_idx(dstp, e, w) >> SHIFT], 1);
    __syncthreads();
    for (int i = t; i < NBUCK; i += 256) hist[i * NB + b] = bins[i];
}

// ---------- src out-degree: privatized packed-uint16 LDS histograms ----------
__global__ __launch_bounds__(256) void k_srchist(const void* __restrict__ srcp,
                                                 unsigned int* __restrict__ partial, int E, int ESB) {
    __shared__ unsigned int bins[NBINS32];   // 100 KB
    __shared__ int shw;
    const int t = threadIdx.x, b = blockIdx.x;
    for (int i = t; i < NBINS32; i += 256) bins[i] = 0;
    bool w = detect_w((const int*)srcp, t, &shw);
    __syncthreads();
    int eend = min(E, (b + 1) * ESB);
    for (int e = b * ESB + t; e < eend; e += 256) {
        int s = load_idx(srcp, e, w);
        atomicAdd(&bins[s >> 1], 1u << ((s & 1) << 4));
    }
    __syncthreads();
    for (int i = t; i < NBINS32; i += 256) partial[(size_t)b * NBINS32 + i] = bins[i];
}

// ---------- pass 2: scan hist (bucket-major) ----------
__global__ __launch_bounds__(256) void k_scanA(int* __restrict__ hist, int* __restrict__ bsum) {
    __shared__ int s[256];
    const int t = threadIdx.x, g = blockIdx.x;
    int v = hist[g * NB + t];
    s[t] = v;
    __syncthreads();
    for (int off = 1; off < 256; off <<= 1) {
        int u = (t >= off) ? s[t - off] : 0;
        __syncthreads();
        s[t] += u;
        __syncthreads();
    }
    hist[g * NB + t] = s[t] - v;
    if (t == 255) bsum[g] = s[255];
}

__global__ __launch_bounds__(512) void k_scanB(const int* __restrict__ bsum, int* __restrict__ bb) {
    __shared__ int s[512];
    const int t = threadIdx.x;
    int v = (t < NBUCK) ? bsum[t] : 0;
    s[t] = v;
    __syncthreads();
    for (int off = 1; off < 512; off <<= 1) {
        int u = (t >= off) ? s[t - off] : 0;
        __syncthreads();
        s[t] += u;
        __syncthreads();
    }
    if (t <= NBUCK) bb[t] = s[t] - v;     // bb[NBUCK] = total = E
}

// ---------- pass 3: coarse scatter, packed (src | dl<<16) ----------
__global__ __launch_bounds__(256) void k_cscatter(const void* __restrict__ srcp,
                                                  const void* __restrict__ dstp,
                                                  const int* __restrict__ hist,
                                                  const int* __restrict__ bb,
                                                  unsigned int* __restrict__ tmp,
                                                  int E, int EPB) {
    __shared__ int cur[NBUCK];
    __shared__ int shw;
    const int t = threadIdx.x, b = blockIdx.x;
    for (int i = t; i < NBUCK; i += 256) cur[i] = hist[i * NB + b] + bb[i];
    bool w = detect_w((const int*)dstp, t, &shw);
    __syncthreads();
    int eend = min(E, (b + 1) * EPB);
    for (int e = b * EPB + t; e < eend; e += 256) {
        int s = load_idx(srcp, e, w);
        int d = load_idx(dstp, e, w);
        int pos = atomicAdd(&cur[d >> SHIFT], 1);
        tmp[pos] = (unsigned int)s | ((unsigned int)(d & 127) << 16);
    }
}

// ---------- pass 4: fine count + scan + scatter; writes rp, innorm, onorm (sred fused) ----------
__global__ __launch_bounds__(256) void k_fine(const unsigned int* __restrict__ tmp,
                                              const int* __restrict__ bb,
                                              const unsigned int* __restrict__ partial,
                                              int* __restrict__ rp,
                                              int* __restrict__ esrc,
                                              float* __restrict__ innorm,
                                              float* __restrict__ onorm) {
    __shared__ int fcnt[128];
    __shared__ int sc[128];
    __shared__ int fcur[128];
    const int t = threadIdx.x, u = blockIdx.x;
    const int e0 = bb[u], e1 = bb[u + 1];
    if (t < 128) fcnt[t] = 0;
    __syncthreads();
    for (int e = e0 + t; e < e1; e += 256)
        atomicAdd(&fcnt[tmp[e] >> 16], 1);
    // fused sred: this block owns packed words u*64 .. u*64+63 (= its own 128 nodes)
    if (t < 64) {
        int wd = u * 64 + t;
        if (wd < NBINS32) {
            int c0 = 0, c1 = 0;
            for (int b = 0; b < SB; ++b) {
                unsigned int v = partial[(size_t)b * NBINS32 + wd];
                c0 += (int)(v & 0xFFFFu);
                c1 += (int)(v >> 16);
            }
            if (c0 < 1) c0 = 1;
            if (c1 < 1) c1 = 1;
            onorm[2 * wd]     = 1.0f / sqrtf((float)c0);
            if (2 * wd + 1 < N_NODES) onorm[2 * wd + 1] = 1.0f / sqrtf((float)c1);
        }
    }
    __syncthreads();
    if (t < 128) sc[t] = fcnt[t];
    __syncthreads();
    for (int off = 1; off < 128; off <<= 1) {
        int v = (t < 128 && t >= off) ? sc[t - off] : 0;
        __syncthreads();
        if (t < 128) sc[t] += v;
        __syncthreads();
    }
    if (t < 128) {
        int base = e0 + sc[t] - fcnt[t];
        fcur[t] = base;
        int node = u * 128 + t;
        if (node < N_NODES) {
            rp[node] = base;
            int c = fcnt[t]; if (c < 1) c = 1;
            innorm[node] = 1.0f / sqrtf((float)c);
        }
    }
    if (u == NBUCK - 1 && t == 0) rp[N_NODES] = e1;
    __syncthreads();
    for (int e = e0 + t; e < e1; e += 256) {
        unsigned int p = tmp[e];
        int pos = atomicAdd(&fcur[p >> 16], 1);
        esrc[pos] = (int)(p & 0xFFFFu);
    }
}

// ---------- GEMM1 (MFMA fp16): X1[n,:] = fp16( out_norm[n] * (feat[n,:] @ W1) ) ----------
#define LDA 40  // 32 + 8 halfs pad (16B)
__global__ __launch_bounds__(256) void k_gemm1_mfma(const float* __restrict__ A,
                                                    const _Float16* __restrict__ BT,
                                                    const float* __restrict__ onorm,
                                                    _Float16* __restrict__ X) {
    __shared__ _Float16 As[64 * LDA];
    __shared__ _Float16 Bs[128 * LDA];
    const int tid  = threadIdx.x;
    const int wave = tid >> 6, lane = tid & 63;
    const int lm = lane & 15, lq = lane >> 4;
    const int row0 = blockIdx.x * 64;

    const int ar = tid >> 2, aq = tid & 3;
    int arow = row0 + ar; if (arow >= N_NODES) arow = N_NODES - 1;
    const float* aptr = A + (size_t)arow * IN_SIZE + aq * 8;
    _Float16* asd = &As[ar * LDA + aq * 8];
    const int bn = tid >> 1, bh = tid & 1;
    const _Float16* bptr = BT + (size_t)bn * IN_SIZE + bh * 16;
    _Float16* bsd = &Bs[bn * LDA + bh * 16];

    f32x4 acc[8];
#pragma unroll
    for (int nt = 0; nt < 8; ++nt) acc[nt] = (f32x4){0.f, 0.f, 0.f, 0.f};

    for (int k0 = 0; k0 < IN_SIZE; k0 += 32) {
        float4 a0 = *(const float4*)(aptr + k0);
        float4 a1 = *(const float4*)(aptr + k0 + 4);
        f16x8  b0 = *(const f16x8*)(bptr + k0);
        f16x8  b1 = *(const f16x8*)(bptr + k0 + 8);
        f16x8 ap = {(_Float16)a0.x, (_Float16)a0.y, (_Float16)a0.z, (_Float16)a0.w,
                    (_Float16)a1.x, (_Float16)a1.y, (_Float16)a1.z, (_Float16)a1.w};
        __syncthreads();
        *(f16x8*)asd       = ap;
        *(f16x8*)bsd       = b0;
        *(f16x8*)(bsd + 8) = b1;
        __syncthreads();
        f16x8 af = *(const f16x8*)&As[(wave * 16 + lm) * LDA + lq * 8];
#pragma unroll
        for (int nt = 0; nt < 8; ++nt) {
            f16x8 bf = *(const f16x8*)&Bs[(nt * 16 + lm) * LDA + lq * 8];
            acc[nt] = __builtin_amdgcn_mfma_f32_16x16x32_f16(af, bf, acc[nt], 0, 0, 0);
        }
    }
#pragma unroll
    for (int i = 0; i < 4; ++i) {
        int row = row0 + wave * 16 + lq * 4 + i;
        if (row < N_NODES) {
            float on = onorm[row];
            _Float16* o = X + (size_t)row * HID + lm;
#pragma unroll
            for (int nt = 0; nt < 8; ++nt)
                o[nt * 16] = (_Float16)(acc[nt][i] * on);
        }
    }
}

// ---------- agg1: H = fp16( relu(gather-sum(X1)*in_norm + b1) * out_norm ) ----------
// one wave per node (max gather parallelism — fusion with gemm2 regressed, r7)
__global__ __launch_bounds__(256) void k_agg1(const _Float16* __restrict__ X, const int* __restrict__ rp,
                                              const int* __restrict__ esrc, const float* __restrict__ innorm,
                                              const float* __restrict__ onorm, const float* __restrict__ b1,
                                              _Float16* __restrict__ H) {
    const int n = blockIdx.x * 4 + (threadIdx.x >> 6);
    const int c = (threadIdx.x & 63) << 1;
    if (n >= N_NODES) return;
    const int e0 = rp[n], e1 = rp[n + 1];
    float a0 = 0.f, a1 = 0.f;
    int e = e0;
    for (; e + 3 < e1; e += 4) {
        int s0 = esrc[e], s1 = esrc[e + 1], s2 = esrc[e + 2], s3 = esrc[e + 3];
        f16x2 v0 = *(const f16x2*)&X[(size_t)s0 * HID + c];
        f16x2 v1 = *(const f16x2*)&X[(size_t)s1 * HID + c];
        f16x2 v2 = *(const f16x2*)&X[(size_t)s2 * HID + c];
        f16x2 v3 = *(const f16x2*)&X[(size_t)s3 * HID + c];
        a0 += ((float)v0.x + (float)v1.x) + ((float)v2.x + (float)v3.x);
        a1 += ((float)v0.y + (float)v1.y) + ((float)v2.y + (float)v3.y);
    }
    for (; e < e1; ++e) {
        f16x2 v = *(const f16x2*)&X[(size_t)esrc[e] * HID + c];
        a0 += (float)v.x; a1 += (float)v.y;
    }
    float inn = innorm[n], on = onorm[n];
    float2 b = *(const float2*)&b1[c];
    float h0 = fmaxf(a0 * inn + b.x, 0.f) * on;
    float h1 = fmaxf(a1 * inn + b.y, 0.f) * on;
    *(f16x2*)&H[(size_t)n * HID + c] = (f16x2){(_Float16)h0, (_Float16)h1};
}

// ---------- GEMM2 (MFMA fp16): X2 = fp16( H @ W2 )   [50000x128 @ 128x64] ----------
#define LDK 136  // 128 + 8 halfs pad
__global__ __launch_bounds__(256) void k_gemm2_mfma(const _Float16* __restrict__ Hm,
                                                    const _Float16* __restrict__ W2T,
                                                    _Float16* __restrict__ X2) {
    __shared__ _Float16 Hs[64 * LDK];
    __shared__ _Float16 Ws[64 * LDK];
    const int tid  = threadIdx.x;
    const int wave = tid >> 6, lane = tid & 63;
    const int lm = lane & 15, lq = lane >> 4;
    const int row0 = blockIdx.x * 64;

    const int r = tid >> 2, cch = (tid & 3) * 32;
    int hrow = row0 + r; if (hrow >= N_NODES) hrow = N_NODES - 1;
    const _Float16* hp = Hm + (size_t)hrow * HID + cch;
    const _Float16* wp = W2T + (size_t)r * HID + cch;
    _Float16* hd = &Hs[r * LDK + cch];
    _Float16* wd = &Ws[r * LDK + cch];
#pragma unroll
    for (int i = 0; i < 4; ++i) {
        *(f16x8*)(hd + i * 8) = *(const f16x8*)(hp + i * 8);
        *(f16x8*)(wd + i * 8) = *(const f16x8*)(wp + i * 8);
    }
    __syncthreads();

    f32x4 acc[4];
#pragma unroll
    for (int nt = 0; nt < 4; ++nt) acc[nt] = (f32x4){0.f, 0.f, 0.f, 0.f};
#pragma unroll
    for (int k0 = 0; k0 < HID; k0 += 32) {
        f16x8 af = *(const f16x8*)&Hs[(wave * 16 + lm) * LDK + k0 + lq * 8];
#pragma unroll
        for (int nt = 0; nt < 4; ++nt) {
            f16x8 bf = *(const f16x8*)&Ws[(nt * 16 + lm) * LDK + k0 + lq * 8];
            acc[nt] = __builtin_amdgcn_mfma_f32_16x16x32_f16(af, bf, acc[nt], 0, 0, 0);
        }
    }
#pragma unroll
    for (int i = 0; i < 4; ++i) {
        int row = row0 + wave * 16 + lq * 4 + i;
        if (row < N_NODES) {
            _Float16* o = X2 + (size_t)row * OUT + lm;
#pragma unroll
            for (int nt = 0; nt < 4; ++nt)
                o[nt * 16] = (_Float16)acc[nt][i];
        }
    }
}

// ---------- agg2: out = gather-sum(X2)*in_norm + b2  (fp32 out) ----------
__global__ __launch_bounds__(256) void k_agg2(const _Float16* __restrict__ X2, const int* __restrict__ rp,
                                              const int* __restrict__ esrc, const float* __restrict__ innorm,
                                              const float* __restrict__ b2, float* __restrict__ out) {
    const int n = blockIdx.x * 8 + (threadIdx.x >> 5);
    const int c = (threadIdx.x & 31) << 1;
    if (n >= N_NODES) return;
    const int e0 = rp[n], e1 = rp[n + 1];
    float a0 = 0.f, a1 = 0.f;
    int e = e0;
    for (; e + 3 < e1; e += 4) {
        int s0 = esrc[e], s1 = esrc[e + 1], s2 = esrc[e + 2], s3 = esrc[e + 3];
        f16x2 v0 = *(const f16x2*)&X2[(size_t)s0 * OUT + c];
        f16x2 v1 = *(const f16x2*)&X2[(size_t)s1 * OUT + c];
        f16x2 v2 = *(const f16x2*)&X2[(size_t)s2 * OUT + c];
        f16x2 v3 = *(const f16x2*)&X2[(size_t)s3 * OUT + c];
        a0 += ((float)v0.x + (float)v1.x) + ((float)v2.x + (float)v3.x);
        a1 += ((float)v0.y + (float)v1.y) + ((float)v2.y + (float)v3.y);
    }
    for (; e < e1; ++e) {
        f16x2 v = *(const f16x2*)&X2[(size_t)esrc[e] * OUT + c];
        a0 += (float)v.x; a1 += (float)v.y;
    }
    float inn = innorm[n];
    float2 b = *(const float2*)&b2[c];
    *(float2*)&out[(size_t)n * OUT + c] = make_float2(a0 * inn + b.x, a1 * inn + b.y);
}

extern "C" void kernel_launch(void* const* d_in, const int* in_sizes, int n_in,
                              void* d_out, int out_size, void* d_ws, size_t ws_size,
                              hipStream_t stream) {
    const float* feat = (const float*)d_in[0];
    const float* W1   = (const float*)d_in[1];
    const float* b1   = (const float*)d_in[2];
    const float* W2   = (const float*)d_in[3];
    const float* b2   = (const float*)d_in[4];
    const void*  srcp = (const void*)d_in[5];
    const void*  dstp = (const void*)d_in[6];
    const int    E    = in_sizes[5];
    float* out = (float*)d_out;

    char* w = (char*)d_ws;
    size_t off = 0;
    auto alloc = [&](size_t bytes) -> void* {
        off = (off + 255) & ~(size_t)255;
        void* p = w + off;
        off += bytes;
        return p;
    };
    int*   hist    = (int*)alloc((size_t)NBUCK * NB * 4);
    int*   bsum    = (int*)alloc((size_t)NBUCK * 4);
    int*   bb      = (int*)alloc((size_t)(NBUCK + 1) * 4);
    int*   rp      = (int*)alloc((size_t)(N_NODES + 1) * 4);
    unsigned int* spart = (unsigned int*)alloc((size_t)SB * NBINS32 * 4);
    unsigned int* tmp   = (unsigned int*)alloc((size_t)E * 4);
    int*   esrc    = (int*)alloc((size_t)E * 4);
    float* onorm   = (float*)alloc((size_t)N_NODES * 4);
    float* innorm  = (float*)alloc((size_t)N_NODES * 4);
    _Float16* W1T  = (_Float16*)alloc((size_t)IN_SIZE * HID * 2);
    _Float16* W2T  = (_Float16*)alloc((size_t)HID * OUT * 2);
    _Float16* X1   = (_Float16*)alloc((size_t)N_NODES * HID * 2);
    _Float16* Hbuf = (_Float16*)alloc((size_t)N_NODES * HID * 2);
    _Float16* X2   = (_Float16*)alloc((size_t)N_NODES * OUT * 2);
    (void)ws_size; (void)n_in; (void)out_size;

    const int EPB = (E + NB - 1) / NB;
    const int ESB = (E + SB - 1) / SB;
    const int WTB = (IN_SIZE * HID + HID * OUT + 255) / 256;

    // CSR build — no global atomics anywhere
    k_chist_wt<<<NB + WTB, 256, 0, stream>>>(dstp, hist, E, EPB, W1, W1T, W2, W2T);
    k_srchist<<<SB, 256, 0, stream>>>(srcp, spart, E, ESB);
    k_scanA<<<NBUCK, 256, 0, stream>>>(hist, bsum);
    k_scanB<<<1, 512, 0, stream>>>(bsum, bb);
    k_cscatter<<<NB, 256, 0, stream>>>(srcp, dstp, hist, bb, tmp, E, EPB);
    k_fine<<<NBUCK, 256, 0, stream>>>(tmp, bb, spart, rp, esrc, innorm, onorm);

    // dense + aggregation pipeline
    k_gemm1_mfma<<<(N_NODES + 63) / 64, 256, 0, stream>>>(feat, W1T, onorm, X1);
    k_agg1<<<(N_NODES + 3) / 4, 256, 0, stream>>>(X1, rp, esrc, innorm, onorm, b1, Hbuf);
    k_gemm2_mfma<<<(N_NODES + 63) / 64, 256, 0, stream>>>(Hbuf, W2T, X2);
    k_agg2<<<(N_NODES + 7) / 8, 256, 0, stream>>>(X2, rp, esrc, innorm, b2, out);
}

// Round 9
// 298.441 us; speedup vs baseline: 1.1429x; 1.0406x over previous
//
#include <hip/hip_runtime.h>

#define N_NODES 50000
#define IN_SIZE 512
#define HID 128
#define OUT 64
#define NB 256                 // coarse scatter blocks
#define SHIFT 7                // bucket = dst >> 7  (128 nodes per bucket)
#define NBUCK 391              // ceil(50000/128)
#define SB 64                  // src-histogram blocks (100KB LDS each)
#define NBINS32 25000          // 50000 uint16 bins packed in uint32

typedef _Float16 f16x8 __attribute__((ext_vector_type(8)));
typedef _Float16 f16x4 __attribute__((ext_vector_type(4)));
typedef _Float16 f16x2 __attribute__((ext_vector_type(2)));
typedef float    f32x4 __attribute__((ext_vector_type(4)));

// ---------- inline int64-vs-int32 layout detection (per block, no extra dispatch) ----------
__device__ __forceinline__ bool detect_w(const int* p, int t, int* sh) {
    if (t < 64) {
        unsigned long long m = __ballot(p[2 * t + 1] == 0);
        if (t == 0) *sh = (m == ~0ull) ? 1 : 0;
    }
    __syncthreads();
    return *sh != 0;
}

__device__ __forceinline__ int load_idx(const void* p, int e, bool w) {
    return w ? (int)((const long long*)p)[e] : ((const int*)p)[e];
}

// ---------- pass 1: per-block coarse histogram of dst (LDS only) + appended weight-transpose blocks ----------
__global__ __launch_bounds__(256) void k_chist_wt(const void* __restrict__ dstp,
                                                  int* __restrict__ hist, int E, int EPB,
                                                  const float* __restrict__ W1, _Float16* __restrict__ W1T,
                                                  const float* __restrict__ W2, _Float16* __restrict__ W2T) {
    const int t = threadIdx.x, b = blockIdx.x;
    if (b >= NB) {   // weight transpose tail blocks
        int i = (b - NB) * 256 + t;
        if (i < IN_SIZE * HID) {
            int k = i >> 7, n = i & (HID - 1);
            W1T[(size_t)n * IN_SIZE + k] = (_Float16)W1[i];
        } else {
            int j = i - IN_SIZE * HID;
            if (j < HID * OUT) {
                int k = j >> 6, n = j & (OUT - 1);
                W2T[(size_t)n * HID + k] = (_Float16)W2[j];
            }
        }
        return;
    }
    __shared__ int bins[NBUCK];
    __shared__ int shw;
    for (int i = t; i < NBUCK; i += 256) bins[i] = 0;
    bool w = detect_w((const int*)dstp, t, &shw);
    __syncthreads();
    int eend = min(E, (b + 1) * EPB);
    for (int e = b * EPB + t; e < eend; e += 256)
        atomicAdd(&bins[load_idx(dstp, e, w) >> SHIFT], 1);
    __syncthreads();
    for (int i = t; i < NBUCK; i += 256) hist[i * NB + b] = bins[i];
}

// ---------- src out-degree: privatized packed-uint16 LDS histograms ----------
__global__ __launch_bounds__(256) void k_srchist(const void* __restrict__ srcp,
                                                 unsigned int* __restrict__ partial, int E, int ESB) {
    __shared__ unsigned int bins[NBINS32];   // 100 KB
    __shared__ int shw;
    const int t = threadIdx.x, b = blockIdx.x;
    for (int i = t; i < NBINS32; i += 256) bins[i] = 0;
    bool w = detect_w((const int*)srcp, t, &shw);
    __syncthreads();
    int eend = min(E, (b + 1) * ESB);
    for (int e = b * ESB + t; e < eend; e += 256) {
        int s = load_idx(srcp, e, w);
        atomicAdd(&bins[s >> 1], 1u << ((s & 1) << 4));
    }
    __syncthreads();
    for (int i = t; i < NBINS32; i += 256) partial[(size_t)b * NBINS32 + i] = bins[i];
}

// ---------- pass 2: scan hist (bucket-major) ----------
__global__ __launch_bounds__(256) void k_scanA(int* __restrict__ hist, int* __restrict__ bsum) {
    __shared__ int s[256];
    const int t = threadIdx.x, g = blockIdx.x;
    int v = hist[g * NB + t];
    s[t] = v;
    __syncthreads();
    for (int off = 1; off < 256; off <<= 1) {
        int u = (t >= off) ? s[t - off] : 0;
        __syncthreads();
        s[t] += u;
        __syncthreads();
    }
    hist[g * NB + t] = s[t] - v;
    if (t == 255) bsum[g] = s[255];
}

__global__ __launch_bounds__(512) void k_scanB(const int* __restrict__ bsum, int* __restrict__ bb) {
    __shared__ int s[512];
    const int t = threadIdx.x;
    int v = (t < NBUCK) ? bsum[t] : 0;
    s[t] = v;
    __syncthreads();
    for (int off = 1; off < 512; off <<= 1) {
        int u = (t >= off) ? s[t - off] : 0;
        __syncthreads();
        s[t] += u;
        __syncthreads();
    }
    if (t <= NBUCK) bb[t] = s[t] - v;     // bb[NBUCK] = total = E
}

// ---------- pass 3: coarse scatter, packed (src | dl<<16) ----------
__global__ __launch_bounds__(256) void k_cscatter(const void* __restrict__ srcp,
                                                  const void* __restrict__ dstp,
                                                  const int* __restrict__ hist,
                                                  const int* __restrict__ bb,
                                                  unsigned int* __restrict__ tmp,
                                                  int E, int EPB) {
    __shared__ int cur[NBUCK];
    __shared__ int shw;
    const int t = threadIdx.x, b = blockIdx.x;
    for (int i = t; i < NBUCK; i += 256) cur[i] = hist[i * NB + b] + bb[i];
    bool w = detect_w((const int*)dstp, t, &shw);
    __syncthreads();
    int eend = min(E, (b + 1) * EPB);
    for (int e = b * EPB + t; e < eend; e += 256) {
        int s = load_idx(srcp, e, w);
        int d = load_idx(dstp, e, w);
        int pos = atomicAdd(&cur[d >> SHIFT], 1);
        tmp[pos] = (unsigned int)s | ((unsigned int)(d & 127) << 16);
    }
}

// ---------- pass 4: fine count + scan + scatter; writes rp, innorm, onorm (sred fused) ----------
__global__ __launch_bounds__(256) void k_fine(const unsigned int* __restrict__ tmp,
                                              const int* __restrict__ bb,
                                              const unsigned int* __restrict__ partial,
                                              int* __restrict__ rp,
                                              int* __restrict__ esrc,
                                              float* __restrict__ innorm,
                                              float* __restrict__ onorm) {
    __shared__ int fcnt[128];
    __shared__ int sc[128];
    __shared__ int fcur[128];
    const int t = threadIdx.x, u = blockIdx.x;
    const int e0 = bb[u], e1 = bb[u + 1];
    if (t < 128) fcnt[t] = 0;
    __syncthreads();
    for (int e = e0 + t; e < e1; e += 256)
        atomicAdd(&fcnt[tmp[e] >> 16], 1);
    // fused sred: this block owns packed words u*64 .. u*64+63 (= its own 128 nodes)
    if (t < 64) {
        int wd = u * 64 + t;
        if (wd < NBINS32) {
            int c0 = 0, c1 = 0;
            for (int b = 0; b < SB; ++b) {
                unsigned int v = partial[(size_t)b * NBINS32 + wd];
                c0 += (int)(v & 0xFFFFu);
                c1 += (int)(v >> 16);
            }
            if (c0 < 1) c0 = 1;
            if (c1 < 1) c1 = 1;
            onorm[2 * wd]     = 1.0f / sqrtf((float)c0);
            if (2 * wd + 1 < N_NODES) onorm[2 * wd + 1] = 1.0f / sqrtf((float)c1);
        }
    }
    __syncthreads();
    if (t < 128) sc[t] = fcnt[t];
    __syncthreads();
    for (int off = 1; off < 128; off <<= 1) {
        int v = (t < 128 && t >= off) ? sc[t - off] : 0;
        __syncthreads();
        if (t < 128) sc[t] += v;
        __syncthreads();
    }
    if (t < 128) {
        int base = e0 + sc[t] - fcnt[t];
        fcur[t] = base;
        int node = u * 128 + t;
        if (node < N_NODES) {
            rp[node] = base;
            int c = fcnt[t]; if (c < 1) c = 1;
            innorm[node] = 1.0f / sqrtf((float)c);
        }
    }
    if (u == NBUCK - 1 && t == 0) rp[N_NODES] = e1;
    __syncthreads();
    for (int e = e0 + t; e < e1; e += 256) {
        unsigned int p = tmp[e];
        int pos = atomicAdd(&fcur[p >> 16], 1);
        esrc[pos] = (int)(p & 0xFFFFu);
    }
}

// ---------- GEMM1 (MFMA fp16): X1[n,:] = fp16( out_norm[n] * (feat[n,:] @ W1) ) ----------
#define LDA 40  // 32 + 8 halfs pad (16B)
__global__ __launch_bounds__(256) void k_gemm1_mfma(const float* __restrict__ A,
                                                    const _Float16* __restrict__ BT,
                                                    const float* __restrict__ onorm,
                                                    _Float16* __restrict__ X) {
    __shared__ _Float16 As[64 * LDA];
    __shared__ _Float16 Bs[128 * LDA];
    const int tid  = threadIdx.x;
    const int wave = tid >> 6, lane = tid & 63;
    const int lm = lane & 15, lq = lane >> 4;
    const int row0 = blockIdx.x * 64;

    const int ar = tid >> 2, aq = tid & 3;
    int arow = row0 + ar; if (arow >= N_NODES) arow = N_NODES - 1;
    const float* aptr = A + (size_t)arow * IN_SIZE + aq * 8;
    _Float16* asd = &As[ar * LDA + aq * 8];
    const int bn = tid >> 1, bh = tid & 1;
    const _Float16* bptr = BT + (size_t)bn * IN_SIZE + bh * 16;
    _Float16* bsd = &Bs[bn * LDA + bh * 16];

    f32x4 acc[8];
#pragma unroll
    for (int nt = 0; nt < 8; ++nt) acc[nt] = (f32x4){0.f, 0.f, 0.f, 0.f};

    for (int k0 = 0; k0 < IN_SIZE; k0 += 32) {
        float4 a0 = *(const float4*)(aptr + k0);
        float4 a1 = *(const float4*)(aptr + k0 + 4);
        f16x8  b0 = *(const f16x8*)(bptr + k0);
        f16x8  b1 = *(const f16x8*)(bptr + k0 + 8);
        f16x8 ap = {(_Float16)a0.x, (_Float16)a0.y, (_Float16)a0.z, (_Float16)a0.w,
                    (_Float16)a1.x, (_Float16)a1.y, (_Float16)a1.z, (_Float16)a1.w};
        __syncthreads();
        *(f16x8*)asd       = ap;
        *(f16x8*)bsd       = b0;
        *(f16x8*)(bsd + 8) = b1;
        __syncthreads();
        f16x8 af = *(const f16x8*)&As[(wave * 16 + lm) * LDA + lq * 8];
#pragma unroll
        for (int nt = 0; nt < 8; ++nt) {
            f16x8 bf = *(const f16x8*)&Bs[(nt * 16 + lm) * LDA + lq * 8];
            acc[nt] = __builtin_amdgcn_mfma_f32_16x16x32_f16(af, bf, acc[nt], 0, 0, 0);
        }
    }
#pragma unroll
    for (int i = 0; i < 4; ++i) {
        int row = row0 + wave * 16 + lq * 4 + i;
        if (row < N_NODES) {
            float on = onorm[row];
            _Float16* o = X + (size_t)row * HID + lm;
#pragma unroll
            for (int nt = 0; nt < 8; ++nt)
                o[nt * 16] = (_Float16)(acc[nt][i] * on);
        }
    }
}

// ---------- agg1: H = fp16( relu(gather-sum(X1)*in_norm + b1) * out_norm ) ----------
// 32 lanes per node, 4 cols/lane (8B f16x4 loads) — 2x outstanding bytes vs 4B loads (r8)
__global__ __launch_bounds__(256) void k_agg1(const _Float16* __restrict__ X, const int* __restrict__ rp,
                                              const int* __restrict__ esrc, const float* __restrict__ innorm,
                                              const float* __restrict__ onorm, const float* __restrict__ b1,
                                              _Float16* __restrict__ H) {
    const int n = blockIdx.x * 8 + (threadIdx.x >> 5);
    const int c = (threadIdx.x & 31) << 2;
    if (n >= N_NODES) return;
    const int e0 = rp[n], e1 = rp[n + 1];
    float a0 = 0.f, a1 = 0.f, a2 = 0.f, a3 = 0.f;
    int e = e0;
    for (; e + 3 < e1; e += 4) {
        int s0 = esrc[e], s1 = esrc[e + 1], s2 = esrc[e + 2], s3 = esrc[e + 3];
        f16x4 v0 = *(const f16x4*)&X[(size_t)s0 * HID + c];
        f16x4 v1 = *(const f16x4*)&X[(size_t)s1 * HID + c];
        f16x4 v2 = *(const f16x4*)&X[(size_t)s2 * HID + c];
        f16x4 v3 = *(const f16x4*)&X[(size_t)s3 * HID + c];
        a0 += ((float)v0.x + (float)v1.x) + ((float)v2.x + (float)v3.x);
        a1 += ((float)v0.y + (float)v1.y) + ((float)v2.y + (float)v3.y);
        a2 += ((float)v0.z + (float)v1.z) + ((float)v2.z + (float)v3.z);
        a3 += ((float)v0.w + (float)v1.w) + ((float)v2.w + (float)v3.w);
    }
    for (; e < e1; ++e) {
        f16x4 v = *(const f16x4*)&X[(size_t)esrc[e] * HID + c];
        a0 += (float)v.x; a1 += (float)v.y; a2 += (float)v.z; a3 += (float)v.w;
    }
    float inn = innorm[n], on = onorm[n];
    float4 b = *(const float4*)&b1[c];
    float h0 = fmaxf(a0 * inn + b.x, 0.f) * on;
    float h1 = fmaxf(a1 * inn + b.y, 0.f) * on;
    float h2 = fmaxf(a2 * inn + b.z, 0.f) * on;
    float h3 = fmaxf(a3 * inn + b.w, 0.f) * on;
    *(f16x4*)&H[(size_t)n * HID + c] =
        (f16x4){(_Float16)h0, (_Float16)h1, (_Float16)h2, (_Float16)h3};
}

// ---------- GEMM2 (MFMA fp16): X2 = fp16( H @ W2 )   [50000x128 @ 128x64] ----------
#define LDK 136  // 128 + 8 halfs pad
__global__ __launch_bounds__(256) void k_gemm2_mfma(const _Float16* __restrict__ Hm,
                                                    const _Float16* __restrict__ W2T,
                                                    _Float16* __restrict__ X2) {
    __shared__ _Float16 Hs[64 * LDK];
    __shared__ _Float16 Ws[64 * LDK];
    const int tid  = threadIdx.x;
    const int wave = tid >> 6, lane = tid & 63;
    const int lm = lane & 15, lq = lane >> 4;
    const int row0 = blockIdx.x * 64;

    const int r = tid >> 2, cch = (tid & 3) * 32;
    int hrow = row0 + r; if (hrow >= N_NODES) hrow = N_NODES - 1;
    const _Float16* hp = Hm + (size_t)hrow * HID + cch;
    const _Float16* wp = W2T + (size_t)r * HID + cch;
    _Float16* hd = &Hs[r * LDK + cch];
    _Float16* wd = &Ws[r * LDK + cch];
#pragma unroll
    for (int i = 0; i < 4; ++i) {
        *(f16x8*)(hd + i * 8) = *(const f16x8*)(hp + i * 8);
        *(f16x8*)(wd + i * 8) = *(const f16x8*)(wp + i * 8);
    }
    __syncthreads();

    f32x4 acc[4];
#pragma unroll
    for (int nt = 0; nt < 4; ++nt) acc[nt] = (f32x4){0.f, 0.f, 0.f, 0.f};
#pragma unroll
    for (int k0 = 0; k0 < HID; k0 += 32) {
        f16x8 af = *(const f16x8*)&Hs[(wave * 16 + lm) * LDK + k0 + lq * 8];
#pragma unroll
        for (int nt = 0; nt < 4; ++nt) {
            f16x8 bf = *(const f16x8*)&Ws[(nt * 16 + lm) * LDK + k0 + lq * 8];
            acc[nt] = __builtin_amdgcn_mfma_f32_16x16x32_f16(af, bf, acc[nt], 0, 0, 0);
        }
    }
#pragma unroll
    for (int i = 0; i < 4; ++i) {
        int row = row0 + wave * 16 + lq * 4 + i;
        if (row < N_NODES) {
            _Float16* o = X2 + (size_t)row * OUT + lm;
#pragma unroll
            for (int nt = 0; nt < 4; ++nt)
                o[nt * 16] = (_Float16)acc[nt][i];
        }
    }
}

// ---------- agg2: out = gather-sum(X2)*in_norm + b2  (fp32 out) ----------
// 16 lanes per node, 4 cols/lane (8B f16x4 loads)
__global__ __launch_bounds__(256) void k_agg2(const _Float16* __restrict__ X2, const int* __restrict__ rp,
                                              const int* __restrict__ esrc, const float* __restrict__ innorm,
                                              const float* __restrict__ b2, float* __restrict__ out) {
    const int n = blockIdx.x * 16 + (threadIdx.x >> 4);
    const int c = (threadIdx.x & 15) << 2;
    if (n >= N_NODES) return;
    const int e0 = rp[n], e1 = rp[n + 1];
    float a0 = 0.f, a1 = 0.f, a2 = 0.f, a3 = 0.f;
    int e = e0;
    for (; e + 3 < e1; e += 4) {
        int s0 = esrc[e], s1 = esrc[e + 1], s2 = esrc[e + 2], s3 = esrc[e + 3];
        f16x4 v0 = *(const f16x4*)&X2[(size_t)s0 * OUT + c];
        f16x4 v1 = *(const f16x4*)&X2[(size_t)s1 * OUT + c];
        f16x4 v2 = *(const f16x4*)&X2[(size_t)s2 * OUT + c];
        f16x4 v3 = *(const f16x4*)&X2[(size_t)s3 * OUT + c];
        a0 += ((float)v0.x + (float)v1.x) + ((float)v2.x + (float)v3.x);
        a1 += ((float)v0.y + (float)v1.y) + ((float)v2.y + (float)v3.y);
        a2 += ((float)v0.z + (float)v1.z) + ((float)v2.z + (float)v3.z);
        a3 += ((float)v0.w + (float)v1.w) + ((float)v2.w + (float)v3.w);
    }
    for (; e < e1; ++e) {
        f16x4 v = *(const f16x4*)&X2[(size_t)esrc[e] * OUT + c];
        a0 += (float)v.x; a1 += (float)v.y; a2 += (float)v.z; a3 += (float)v.w;
    }
    float inn = innorm[n];
    float4 b = *(const float4*)&b2[c];
    *(float4*)&out[(size_t)n * OUT + c] =
        make_float4(a0 * inn + b.x, a1 * inn + b.y, a2 * inn + b.z, a3 * inn + b.w);
}

extern "C" void kernel_launch(void* const* d_in, const int* in_sizes, int n_in,
                              void* d_out, int out_size, void* d_ws, size_t ws_size,
                              hipStream_t stream) {
    const float* feat = (const float*)d_in[0];
    const float* W1   = (const float*)d_in[1];
    const float* b1   = (const float*)d_in[2];
    const float* W2   = (const float*)d_in[3];
    const float* b2   = (const float*)d_in[4];
    const void*  srcp = (const void*)d_in[5];
    const void*  dstp = (const void*)d_in[6];
    const int    E    = in_sizes[5];
    float* out = (float*)d_out;

    char* w = (char*)d_ws;
    size_t off = 0;
    auto alloc = [&](size_t bytes) -> void* {
        off = (off + 255) & ~(size_t)255;
        void* p = w + off;
        off += bytes;
        return p;
    };
    int*   hist    = (int*)alloc((size_t)NBUCK * NB * 4);
    int*   bsum    = (int*)alloc((size_t)NBUCK * 4);
    int*   bb      = (int*)alloc((size_t)(NBUCK + 1) * 4);
    int*   rp      = (int*)alloc((size_t)(N_NODES + 1) * 4);
    unsigned int* spart = (unsigned int*)alloc((size_t)SB * NBINS32 * 4);
    unsigned int* tmp   = (unsigned int*)alloc((size_t)E * 4);
    int*   esrc    = (int*)alloc((size_t)E * 4);
    float* onorm   = (float*)alloc((size_t)N_NODES * 4);
    float* innorm  = (float*)alloc((size_t)N_NODES * 4);
    _Float16* W1T  = (_Float16*)alloc((size_t)IN_SIZE * HID * 2);
    _Float16* W2T  = (_Float16*)alloc((size_t)HID * OUT * 2);
    _Float16* X1   = (_Float16*)alloc((size_t)N_NODES * HID * 2);
    _Float16* Hbuf = (_Float16*)alloc((size_t)N_NODES * HID * 2);
    _Float16* X2   = (_Float16*)alloc((size_t)N_NODES * OUT * 2);
    (void)ws_size; (void)n_in; (void)out_size;

    const int EPB = (E + NB - 1) / NB;
    const int ESB = (E + SB - 1) / SB;
    const int WTB = (IN_SIZE * HID + HID * OUT + 255) / 256;

    // CSR build — no global atomics anywhere
    k_chist_wt<<<NB + WTB, 256, 0, stream>>>(dstp, hist, E, EPB, W1, W1T, W2, W2T);
    k_srchist<<<SB, 256, 0, stream>>>(srcp, spart, E, ESB);
    k_scanA<<<NBUCK, 256, 0, stream>>>(hist, bsum);
    k_scanB<<<1, 512, 0, stream>>>(bsum, bb);
    k_cscatter<<<NB, 256, 0, stream>>>(srcp, dstp, hist, bb, tmp, E, EPB);
    k_fine<<<NBUCK, 256, 0, stream>>>(tmp, bb, spart, rp, esrc, innorm, onorm);

    // dense + aggregation pipeline
    k_gemm1_mfma<<<(N_NODES + 63) / 64, 256, 0, stream>>>(feat, W1T, onorm, X1);
    k_agg1<<<(N_NODES + 7) / 8, 256, 0, stream>>>(X1, rp, esrc, innorm, onorm, b1, Hbuf);
    k_gemm2_mfma<<<(N_NODES + 63) / 64, 256, 0, stream>>>(Hbuf, W2T, X2);
    k_agg2<<<(N_NODES + 15) / 16, 256, 0, stream>>>(X2, rp, esrc, innorm, b2, out);
}